// Round 1
// baseline (659.750 us; speedup 1.0000x reference)
//
#include <hip/hip_runtime.h>
#include <hip/hip_bf16.h>
#include <math.h>

typedef __bf16 bf16_t;
typedef __attribute__((ext_vector_type(8))) __bf16 bf16x8;
typedef __attribute__((ext_vector_type(4))) __bf16 bf16x4;
typedef __attribute__((ext_vector_type(4))) float f32x4;

#define MFMA_16x16x32(A_, B_, C_) __builtin_amdgcn_mfma_f32_16x16x32_bf16((A_), (B_), (C_), 0, 0, 0)

#define Bsz 4
#define Ssz 2048
#define Dsz 1024
#define Hh 16
#define DKd 64
#define Mrows (Bsz * Ssz)  /* 8192 */
#define N1 (3 * Dsz)       /* 3072 */
#define KD Dsz             /* 1024 */

// ---------------- f32 -> bf16 conversion (x4 vectorized) ----------------
__global__ void cvt_f32_bf16_kernel(const float* __restrict__ src, bf16_t* __restrict__ dst, int n4) {
  int i = blockIdx.x * blockDim.x + threadIdx.x;
  if (i >= n4) return;
  float4 v = reinterpret_cast<const float4*>(src)[i];
  bf16x4 o = {(bf16_t)v.x, (bf16_t)v.y, (bf16_t)v.z, (bf16_t)v.w};
  reinterpret_cast<bf16x4*>(dst)[i] = o;
}

// ---------------- RoPE cos/sin table: [S][32] float2 ----------------
__global__ void rope_tab_kernel(const int* __restrict__ pos, float2* __restrict__ tab) {
  int i = blockIdx.x * blockDim.x + threadIdx.x;
  if (i >= Ssz * 32) return;
  int s = i >> 5, f = i & 31;
  float inv_freq = powf(10000.0f, -(float)(2 * f) / 64.0f);
  float a = (float)pos[s] * inv_freq;
  tab[i] = make_float2(cosf(a), sinf(a));
}

// ---------------- TN GEMM: C[M][N] = A[M][K] * Bt[N][K]^T ----------------
// 128x128 tile, BK=32, 4 waves (2x2), each wave 64x64 via 4x4 16x16x32 mfma.
// EPI 0: qkv epilogue (RoPE on q/k via lane-pair shfl, scatter to q/k/vT bufs)
// EPI 1: plain f32 store
template <int EPI>
__global__ __launch_bounds__(256, 2) void gemm_tn_kernel(
    const bf16_t* __restrict__ A, const bf16_t* __restrict__ Bt, int Kdim, int ldcN,
    bf16_t* __restrict__ qb, bf16_t* __restrict__ kb, bf16_t* __restrict__ vtb,
    const float2* __restrict__ tab, float* __restrict__ fout) {
  constexpr int LDA = 40;  // 32 + 8 pad: breaks ds_read_b128 bank conflicts
  __shared__ __align__(16) bf16_t As[128 * LDA];
  __shared__ __align__(16) bf16_t Bs[128 * LDA];
  const int t = threadIdx.x;
  const int w = t >> 6, l = t & 63;
  const int lr = l & 15, lk = l >> 4;
  const int wm = w >> 1, wn = w & 1;
  const int m0 = blockIdx.y * 128, n0 = blockIdx.x * 128;

  // staging: thread t owns 16B chunks (row srow, cols scol..scol+8) and (+64 rows)
  const int srow = t >> 2;
  const int scol = (t & 3) * 8;
  const bf16_t* gA0 = A + (size_t)(m0 + srow) * Kdim + scol;
  const bf16_t* gA1 = A + (size_t)(m0 + 64 + srow) * Kdim + scol;
  const bf16_t* gB0 = Bt + (size_t)(n0 + srow) * Kdim + scol;
  const bf16_t* gB1 = Bt + (size_t)(n0 + 64 + srow) * Kdim + scol;
  bf16_t* sA0 = As + srow * LDA + scol;
  bf16_t* sA1 = As + (64 + srow) * LDA + scol;
  bf16_t* sB0 = Bs + srow * LDA + scol;
  bf16_t* sB1 = Bs + (64 + srow) * LDA + scol;

  f32x4 acc[4][4] = {};

  for (int kt = 0; kt < Kdim; kt += 32) {
    // issue global loads early (overlap with previous compute)
    bf16x8 ra0 = *reinterpret_cast<const bf16x8*>(gA0 + kt);
    bf16x8 ra1 = *reinterpret_cast<const bf16x8*>(gA1 + kt);
    bf16x8 rb0 = *reinterpret_cast<const bf16x8*>(gB0 + kt);
    bf16x8 rb1 = *reinterpret_cast<const bf16x8*>(gB1 + kt);
    __syncthreads();  // previous compute done before overwrite
    *reinterpret_cast<bf16x8*>(sA0) = ra0;
    *reinterpret_cast<bf16x8*>(sA1) = ra1;
    *reinterpret_cast<bf16x8*>(sB0) = rb0;
    *reinterpret_cast<bf16x8*>(sB1) = rb1;
    __syncthreads();
    bf16x8 af[4], bfv[4];
#pragma unroll
    for (int m = 0; m < 4; ++m)
      af[m] = *reinterpret_cast<const bf16x8*>(As + (wm * 64 + m * 16 + lr) * LDA + lk * 8);
#pragma unroll
    for (int n = 0; n < 4; ++n)
      bfv[n] = *reinterpret_cast<const bf16x8*>(Bs + (wn * 64 + n * 16 + lr) * LDA + lk * 8);
#pragma unroll
    for (int m = 0; m < 4; ++m)
#pragma unroll
      for (int n = 0; n < 4; ++n)
        acc[m][n] = MFMA_16x16x32(af[m], bfv[n], acc[m][n]);
  }

  if (EPI == 0) {
    // C/D layout: row = lk*4 + r, col = lr (within each 16x16 frag)
#pragma unroll
    for (int n = 0; n < 4; ++n) {
      const int col = n0 + wn * 64 + n * 16 + lr;
      const int sect = col >> 10;       // 0=q 1=k 2=v (uniform across wave)
      const int h = (col >> 6) & 15;
      const int dk = col & 63;
#pragma unroll
      for (int m = 0; m < 4; ++m) {
        const int growb = m0 + wm * 64 + m * 16 + lk * 4;
#pragma unroll
        for (int r = 0; r < 4; ++r) {
          const int grow = growb + r;
          const int bb = grow >> 11;
          const int s = grow & (Ssz - 1);
          float v = acc[m][n][r];
          if (sect < 2) {
            const float pv = __shfl_xor(v, 1);  // paired dk^1 element (same row)
            const float2 cs = tab[(s << 5) | (dk >> 1)];
            // even dk: x1*cos - x2*sin ; odd dk: x1*sin + x2*cos
            float vr = (dk & 1) ? (pv * cs.y + v * cs.x) : (v * cs.x - pv * cs.y);
            const size_t idx = ((size_t)((bb * Hh + h) * Ssz + s)) * DKd + dk;
            if (sect == 0)
              qb[idx] = (bf16_t)(vr * 0.125f);  // fold 1/sqrt(d_k) into q
            else
              kb[idx] = (bf16_t)vr;
          } else {
            // V transposed: [bh][dk][S]
            vtb[((size_t)(bb * Hh + h) * DKd + dk) * Ssz + s] = (bf16_t)v;
          }
        }
      }
    }
  } else {
#pragma unroll
    for (int m = 0; m < 4; ++m)
#pragma unroll
      for (int r = 0; r < 4; ++r) {
        const int grow = m0 + wm * 64 + m * 16 + lk * 4 + r;
        float* op = fout + (size_t)grow * ldcN + n0 + wn * 64 + lr;
#pragma unroll
        for (int n = 0; n < 4; ++n) op[n * 16] = acc[m][n][r];
      }
  }
}

// ---------------- causal flash attention ----------------
// grid: (S/64, B*H); 4 waves, wave w owns q rows [qt*64+16w, +16)
__global__ __launch_bounds__(256, 2) void attn_kernel(
    const bf16_t* __restrict__ qb, const bf16_t* __restrict__ kb,
    const bf16_t* __restrict__ vtb, bf16_t* __restrict__ aout) {
  __shared__ __align__(16) bf16_t Pl[4][16 * 40];  // per-wave P tile, padded
  const int t = threadIdx.x, w = t >> 6, l = t & 63;
  const int lr = l & 15, lk = l >> 4;
  const int bh = blockIdx.y;
  const int qt = blockIdx.x;
  const int q0 = qt * 64 + w * 16;

  const bf16_t* qbase = qb + ((size_t)bh * Ssz + q0) * DKd;
  bf16x8 qf0 = *reinterpret_cast<const bf16x8*>(qbase + lr * DKd + lk * 8);
  bf16x8 qf1 = *reinterpret_cast<const bf16x8*>(qbase + lr * DKd + 32 + lk * 8);

  f32x4 o[4] = {};
  float mrow[4] = {-INFINITY, -INFINITY, -INFINITY, -INFINITY};
  float lrow[4] = {0.f, 0.f, 0.f, 0.f};
  const int kvend = qt * 64 + 64;
  bf16_t* pw = Pl[w];

  for (int kv = 0; kv < kvend; kv += 32) {
    f32x4 sa0 = {}, sa1 = {};
    {
      const bf16_t* kp0 = kb + ((size_t)bh * Ssz + kv) * DKd;
      bf16x8 k00 = *reinterpret_cast<const bf16x8*>(kp0 + lr * DKd + lk * 8);
      bf16x8 k01 = *reinterpret_cast<const bf16x8*>(kp0 + lr * DKd + 32 + lk * 8);
      sa0 = MFMA_16x16x32(qf0, k00, sa0);
      sa0 = MFMA_16x16x32(qf1, k01, sa0);
      const bf16_t* kp1 = kp0 + 16 * DKd;
      bf16x8 k10 = *reinterpret_cast<const bf16x8*>(kp1 + lr * DKd + lk * 8);
      bf16x8 k11 = *reinterpret_cast<const bf16x8*>(kp1 + lr * DKd + 32 + lk * 8);
      sa1 = MFMA_16x16x32(qf0, k10, sa1);
      sa1 = MFMA_16x16x32(qf1, k11, sa1);
    }
    float scl[4];
#pragma unroll
    for (int r = 0; r < 4; ++r) {
      const int rowi = q0 + lk * 4 + r;
      if (kv + lr > rowi) sa0[r] = -INFINITY;
      if (kv + 16 + lr > rowi) sa1[r] = -INFINITY;
      float mx = fmaxf(sa0[r], sa1[r]);
      mx = fmaxf(mx, __shfl_xor(mx, 1));
      mx = fmaxf(mx, __shfl_xor(mx, 2));
      mx = fmaxf(mx, __shfl_xor(mx, 4));
      mx = fmaxf(mx, __shfl_xor(mx, 8));
      const float mnew = fmaxf(mrow[r], mx);
      scl[r] = __expf(mrow[r] - mnew);
      mrow[r] = mnew;
      const float p0 = __expf(sa0[r] - mnew);
      const float p1 = __expf(sa1[r] - mnew);
      sa0[r] = p0;
      sa1[r] = p1;
      float rs = p0 + p1;
      rs += __shfl_xor(rs, 1);
      rs += __shfl_xor(rs, 2);
      rs += __shfl_xor(rs, 4);
      rs += __shfl_xor(rs, 8);
      lrow[r] = lrow[r] * scl[r] + rs;
    }
#pragma unroll
    for (int n = 0; n < 4; ++n)
#pragma unroll
      for (int r = 0; r < 4; ++r) o[n][r] *= scl[r];
    // P -> LDS (re-layout C-frag -> A-frag)
#pragma unroll
    for (int r = 0; r < 4; ++r) {
      pw[(lk * 4 + r) * 40 + lr] = (bf16_t)sa0[r];
      pw[(lk * 4 + r) * 40 + 16 + lr] = (bf16_t)sa1[r];
    }
    __syncthreads();
    bf16x8 pf = *reinterpret_cast<const bf16x8*>(pw + lr * 40 + lk * 8);
#pragma unroll
    for (int n = 0; n < 4; ++n) {
      const bf16x8 vf = *reinterpret_cast<const bf16x8*>(
          vtb + ((size_t)bh * DKd + n * 16 + lr) * Ssz + kv + lk * 8);
      o[n] = MFMA_16x16x32(pf, vf, o[n]);
    }
    __syncthreads();
  }
  const int b_ = bh >> 4, h_ = bh & 15;
#pragma unroll
  for (int r = 0; r < 4; ++r) {
    const float inv = 1.0f / lrow[r];
    const int srowi = q0 + lk * 4 + r;
    bf16_t* op = aout + ((size_t)b_ * Ssz + srowi) * Dsz + h_ * DKd;
#pragma unroll
    for (int n = 0; n < 4; ++n) op[n * 16 + lr] = (bf16_t)(o[n][r] * inv);
  }
}

extern "C" void kernel_launch(void* const* d_in, const int* in_sizes, int n_in,
                              void* d_out, int out_size, void* d_ws, size_t ws_size,
                              hipStream_t stream) {
  const float* x = (const float*)d_in[0];
  const int* pos = (const int*)d_in[1];
  const float* wqkv = (const float*)d_in[2];
  const float* wo = (const float*)d_in[3];
  float* out = (float*)d_out;

  // workspace carve (bf16 elements); aout aliases xb (xb dead after gemm1)
  bf16_t* xb = (bf16_t*)d_ws;                        // 8192*1024
  bf16_t* wqkvb = xb + (size_t)Mrows * KD;           // 3072*1024
  bf16_t* wob = wqkvb + (size_t)N1 * KD;             // 1024*1024
  bf16_t* qbuf = wob + (size_t)Dsz * KD;             // 64*2048*64
  bf16_t* kbuf = qbuf + (size_t)64 * Ssz * DKd;
  bf16_t* vtb = kbuf + (size_t)64 * Ssz * DKd;
  float2* tab = (float2*)(vtb + (size_t)64 * Ssz * DKd);  // 2048*32 float2
  bf16_t* aout = xb;

  {
    int n4 = Mrows * KD / 4;
    cvt_f32_bf16_kernel<<<(n4 + 255) / 256, 256, 0, stream>>>(x, xb, n4);
  }
  {
    int n4 = N1 * KD / 4;
    cvt_f32_bf16_kernel<<<(n4 + 255) / 256, 256, 0, stream>>>(wqkv, wqkvb, n4);
  }
  {
    int n4 = Dsz * KD / 4;
    cvt_f32_bf16_kernel<<<(n4 + 255) / 256, 256, 0, stream>>>(wo, wob, n4);
  }
  rope_tab_kernel<<<(Ssz * 32 + 255) / 256, 256, 0, stream>>>(pos, tab);

  gemm_tn_kernel<0><<<dim3(N1 / 128, Mrows / 128), 256, 0, stream>>>(
      xb, wqkvb, KD, 0, qbuf, kbuf, vtb, tab, nullptr);

  attn_kernel<<<dim3(Ssz / 64, Bsz * Hh), 256, 0, stream>>>(qbuf, kbuf, vtb, aout);

  gemm_tn_kernel<1><<<dim3(Dsz / 128, Mrows / 128), 256, 0, stream>>>(
      aout, wob, KD, Dsz, nullptr, nullptr, nullptr, nullptr, out);
}

// Round 2
// 410.341 us; speedup vs baseline: 1.6078x; 1.6078x over previous
//
#include <hip/hip_runtime.h>
#include <hip/hip_bf16.h>
#include <math.h>

typedef __bf16 bf16_t;
typedef __attribute__((ext_vector_type(8))) __bf16 bf16x8;
typedef __attribute__((ext_vector_type(4))) __bf16 bf16x4;
typedef __attribute__((ext_vector_type(4))) float f32x4;

#define MFMA_16x16x32(A_, B_, C_) __builtin_amdgcn_mfma_f32_16x16x32_bf16((A_), (B_), (C_), 0, 0, 0)

#define Bsz 4
#define Ssz 2048
#define Dsz 1024
#define Hh 16
#define DKd 64
#define Mrows (Bsz * Ssz)  /* 8192 */
#define N1 (3 * Dsz)       /* 3072 */
#define KD Dsz             /* 1024 */

// ---------------- f32 -> bf16 conversion (x4 vectorized) ----------------
__global__ void cvt_f32_bf16_kernel(const float* __restrict__ src, bf16_t* __restrict__ dst, int n4) {
  int i = blockIdx.x * blockDim.x + threadIdx.x;
  if (i >= n4) return;
  float4 v = reinterpret_cast<const float4*>(src)[i];
  bf16x4 o = {(bf16_t)v.x, (bf16_t)v.y, (bf16_t)v.z, (bf16_t)v.w};
  reinterpret_cast<bf16x4*>(dst)[i] = o;
}

// ---------------- RoPE cos/sin table: [S][32] float2 ----------------
__global__ void rope_tab_kernel(const int* __restrict__ pos, float2* __restrict__ tab) {
  int i = blockIdx.x * blockDim.x + threadIdx.x;
  if (i >= Ssz * 32) return;
  int s = i >> 5, f = i & 31;
  float inv_freq = powf(10000.0f, -(float)(2 * f) / 64.0f);
  float a = (float)pos[s] * inv_freq;
  tab[i] = make_float2(cosf(a), sinf(a));
}

// ---------------- TN GEMM: C[M][N] = A[M][K] * Bt[N][K]^T ----------------
// 128x128 tile, BK=32, 4 waves (2x2), each wave 64x64 via 4x4 16x16x32 mfma.
template <int EPI>
__global__ __launch_bounds__(256, 2) void gemm_tn_kernel(
    const bf16_t* __restrict__ A, const bf16_t* __restrict__ Bt, int Kdim, int ldcN,
    bf16_t* __restrict__ qb, bf16_t* __restrict__ kb, bf16_t* __restrict__ vtb,
    const float2* __restrict__ tab, float* __restrict__ fout) {
  constexpr int LDA = 40;  // 32 + 8 pad: breaks ds_read_b128 bank conflicts
  __shared__ __align__(16) bf16_t As[128 * LDA];
  __shared__ __align__(16) bf16_t Bs[128 * LDA];
  const int t = threadIdx.x;
  const int w = t >> 6, l = t & 63;
  const int lr = l & 15, lk = l >> 4;
  const int wm = w >> 1, wn = w & 1;
  const int m0 = blockIdx.y * 128, n0 = blockIdx.x * 128;

  const int srow = t >> 2;
  const int scol = (t & 3) * 8;
  const bf16_t* gA0 = A + (size_t)(m0 + srow) * Kdim + scol;
  const bf16_t* gA1 = A + (size_t)(m0 + 64 + srow) * Kdim + scol;
  const bf16_t* gB0 = Bt + (size_t)(n0 + srow) * Kdim + scol;
  const bf16_t* gB1 = Bt + (size_t)(n0 + 64 + srow) * Kdim + scol;
  bf16_t* sA0 = As + srow * LDA + scol;
  bf16_t* sA1 = As + (64 + srow) * LDA + scol;
  bf16_t* sB0 = Bs + srow * LDA + scol;
  bf16_t* sB1 = Bs + (64 + srow) * LDA + scol;

  f32x4 acc[4][4] = {};

  for (int kt = 0; kt < Kdim; kt += 32) {
    bf16x8 ra0 = *reinterpret_cast<const bf16x8*>(gA0 + kt);
    bf16x8 ra1 = *reinterpret_cast<const bf16x8*>(gA1 + kt);
    bf16x8 rb0 = *reinterpret_cast<const bf16x8*>(gB0 + kt);
    bf16x8 rb1 = *reinterpret_cast<const bf16x8*>(gB1 + kt);
    __syncthreads();
    *reinterpret_cast<bf16x8*>(sA0) = ra0;
    *reinterpret_cast<bf16x8*>(sA1) = ra1;
    *reinterpret_cast<bf16x8*>(sB0) = rb0;
    *reinterpret_cast<bf16x8*>(sB1) = rb1;
    __syncthreads();
    bf16x8 af[4], bfv[4];
#pragma unroll
    for (int m = 0; m < 4; ++m)
      af[m] = *reinterpret_cast<const bf16x8*>(As + (wm * 64 + m * 16 + lr) * LDA + lk * 8);
#pragma unroll
    for (int n = 0; n < 4; ++n)
      bfv[n] = *reinterpret_cast<const bf16x8*>(Bs + (wn * 64 + n * 16 + lr) * LDA + lk * 8);
#pragma unroll
    for (int m = 0; m < 4; ++m)
#pragma unroll
      for (int n = 0; n < 4; ++n)
        acc[m][n] = MFMA_16x16x32(af[m], bfv[n], acc[m][n]);
  }

  if (EPI == 0) {
#pragma unroll
    for (int n = 0; n < 4; ++n) {
      const int col = n0 + wn * 64 + n * 16 + lr;
      const int sect = col >> 10;       // 0=q 1=k 2=v (uniform across wave)
      const int h = (col >> 6) & 15;
      const int dk = col & 63;
#pragma unroll
      for (int m = 0; m < 4; ++m) {
        const int growb = m0 + wm * 64 + m * 16 + lk * 4;
#pragma unroll
        for (int r = 0; r < 4; ++r) {
          const int grow = growb + r;
          const int bb = grow >> 11;
          const int s = grow & (Ssz - 1);
          float v = acc[m][n][r];
          if (sect < 2) {
            const float pv = __shfl_xor(v, 1);  // paired dk^1 element (same row)
            const float2 cs = tab[(s << 5) | (dk >> 1)];
            float vr = (dk & 1) ? (pv * cs.y + v * cs.x) : (v * cs.x - pv * cs.y);
            const size_t idx = ((size_t)((bb * Hh + h) * Ssz + s)) * DKd + dk;
            if (sect == 0)
              qb[idx] = (bf16_t)(vr * 0.125f);  // fold 1/sqrt(d_k) into q
            else
              kb[idx] = (bf16_t)vr;
          } else {
            vtb[((size_t)(bb * Hh + h) * DKd + dk) * Ssz + s] = (bf16_t)v;
          }
        }
      }
    }
  } else {
#pragma unroll
    for (int m = 0; m < 4; ++m)
#pragma unroll
      for (int r = 0; r < 4; ++r) {
        const int grow = m0 + wm * 64 + m * 16 + lk * 4 + r;
        float* op = fout + (size_t)grow * ldcN + n0 + wn * 64 + lr;
#pragma unroll
        for (int n = 0; n < 4; ++n) op[n * 16] = acc[m][n][r];
      }
  }
}

// ---------------- causal flash attention ----------------
// 1D grid, heavy-first: bid -> qt = 31 - bid/64, bh = bid%64.
// 4 waves, wave w owns q rows [qt*64 + 16w, +16); KV step 64; NO barriers
// (P tile is per-wave). Row-sum kept per-lane, reduced once at the end.
__global__ __launch_bounds__(256, 4) void attn_kernel(
    const bf16_t* __restrict__ qb, const bf16_t* __restrict__ kb,
    const bf16_t* __restrict__ vtb, bf16_t* __restrict__ aout) {
  __shared__ __align__(16) bf16_t Pl[4][16 * 72];  // per-wave 16x64 P tile, padded
  const int t = threadIdx.x, w = t >> 6, l = t & 63;
  const int lr = l & 15, lk = l >> 4;
  const int bid = blockIdx.x;
  const int qt = (Ssz / 64 - 1) - (bid >> 6);  // heavy tiles first (LPT)
  const int bh = bid & 63;
  const int q0 = qt * 64 + w * 16;

  const bf16_t* qbase = qb + ((size_t)bh * Ssz + q0) * DKd;
  const bf16x8 qf0 = *reinterpret_cast<const bf16x8*>(qbase + lr * DKd + lk * 8);
  const bf16x8 qf1 = *reinterpret_cast<const bf16x8*>(qbase + lr * DKd + 32 + lk * 8);

  f32x4 o[4] = {};
  float mrow[4] = {-INFINITY, -INFINITY, -INFINITY, -INFINITY};
  float lsum[4] = {0.f, 0.f, 0.f, 0.f};
  bf16_t* pw = Pl[w];
  const int kvend = qt * 64 + 64;
  const bf16_t* kbh = kb + (size_t)bh * Ssz * DKd;
  const bf16_t* vbh = vtb + (size_t)bh * DKd * Ssz;

  for (int kv = 0; kv < kvend; kv += 64) {
    // ---- QK^T over a 16(q) x 64(kv) tile ----
    f32x4 sa[4];
#pragma unroll
    for (int n = 0; n < 4; ++n) {
      const bf16_t* kp = kbh + (size_t)(kv + n * 16) * DKd;
      const bf16x8 b0 = *reinterpret_cast<const bf16x8*>(kp + lr * DKd + lk * 8);
      const bf16x8 b1 = *reinterpret_cast<const bf16x8*>(kp + lr * DKd + 32 + lk * 8);
      f32x4 z = {};
      z = MFMA_16x16x32(qf0, b0, z);
      z = MFMA_16x16x32(qf1, b1, z);
      sa[n] = z;
    }
    // ---- causal mask: only the diagonal 64-block needs it (uniform branch) ----
    if (kv + 64 >= kvend) {
#pragma unroll
      for (int n = 0; n < 4; ++n) {
        const int col = kv + n * 16 + lr;
#pragma unroll
        for (int r = 0; r < 4; ++r)
          if (col > q0 + lk * 4 + r) sa[n][r] = -INFINITY;
      }
    }
    // ---- online softmax (max-reduce only; sum deferred per-lane) ----
#pragma unroll
    for (int r = 0; r < 4; ++r) {
      float mx = fmaxf(fmaxf(sa[0][r], sa[1][r]), fmaxf(sa[2][r], sa[3][r]));
      mx = fmaxf(mx, __shfl_xor(mx, 1));
      mx = fmaxf(mx, __shfl_xor(mx, 2));
      mx = fmaxf(mx, __shfl_xor(mx, 4));
      mx = fmaxf(mx, __shfl_xor(mx, 8));
      const float mnew = fmaxf(mrow[r], mx);
      const float scl = __expf(mrow[r] - mnew);
      mrow[r] = mnew;
      float ps = 0.f;
#pragma unroll
      for (int n = 0; n < 4; ++n) {
        const float p = __expf(sa[n][r] - mnew);
        sa[n][r] = p;
        ps += p;
      }
      lsum[r] = lsum[r] * scl + ps;
#pragma unroll
      for (int n = 0; n < 4; ++n) o[n][r] *= scl;
    }
    // ---- P -> per-wave LDS (C-frag -> A-frag relayout), no barrier needed ----
#pragma unroll
    for (int r = 0; r < 4; ++r)
#pragma unroll
      for (int n = 0; n < 4; ++n)
        pw[(lk * 4 + r) * 72 + n * 16 + lr] = (bf16_t)sa[n][r];
    const bf16x8 pf0 = *reinterpret_cast<const bf16x8*>(pw + lr * 72 + lk * 8);
    const bf16x8 pf1 = *reinterpret_cast<const bf16x8*>(pw + lr * 72 + 32 + lk * 8);
    // ---- PV: o[16q x 64d] += P[16q x 64kv] * V^T[64d x 64kv]^T ----
#pragma unroll
    for (int n = 0; n < 4; ++n) {
      const bf16_t* vp = vbh + (size_t)(n * 16 + lr) * Ssz + kv;
      const bf16x8 v0 = *reinterpret_cast<const bf16x8*>(vp + lk * 8);
      const bf16x8 v1 = *reinterpret_cast<const bf16x8*>(vp + 32 + lk * 8);
      o[n] = MFMA_16x16x32(pf0, v0, o[n]);
      o[n] = MFMA_16x16x32(pf1, v1, o[n]);
    }
  }
  // ---- final cross-lane denominator reduce ----
#pragma unroll
  for (int r = 0; r < 4; ++r) {
    float s = lsum[r];
    s += __shfl_xor(s, 1);
    s += __shfl_xor(s, 2);
    s += __shfl_xor(s, 4);
    s += __shfl_xor(s, 8);
    lsum[r] = s;
  }
  const int b_ = bh >> 4, h_ = bh & 15;
#pragma unroll
  for (int r = 0; r < 4; ++r) {
    const float inv = 1.0f / lsum[r];
    const int srowi = q0 + lk * 4 + r;
    bf16_t* op = aout + ((size_t)b_ * Ssz + srowi) * Dsz + h_ * DKd;
#pragma unroll
    for (int n = 0; n < 4; ++n) op[n * 16 + lr] = (bf16_t)(o[n][r] * inv);
  }
}

extern "C" void kernel_launch(void* const* d_in, const int* in_sizes, int n_in,
                              void* d_out, int out_size, void* d_ws, size_t ws_size,
                              hipStream_t stream) {
  const float* x = (const float*)d_in[0];
  const int* pos = (const int*)d_in[1];
  const float* wqkv = (const float*)d_in[2];
  const float* wo = (const float*)d_in[3];
  float* out = (float*)d_out;

  bf16_t* xb = (bf16_t*)d_ws;                        // 8192*1024
  bf16_t* wqkvb = xb + (size_t)Mrows * KD;           // 3072*1024
  bf16_t* wob = wqkvb + (size_t)N1 * KD;             // 1024*1024
  bf16_t* qbuf = wob + (size_t)Dsz * KD;             // 64*2048*64
  bf16_t* kbuf = qbuf + (size_t)64 * Ssz * DKd;
  bf16_t* vtb = kbuf + (size_t)64 * Ssz * DKd;
  float2* tab = (float2*)(vtb + (size_t)64 * Ssz * DKd);  // 2048*32 float2
  bf16_t* aout = xb;

  {
    int n4 = Mrows * KD / 4;
    cvt_f32_bf16_kernel<<<(n4 + 255) / 256, 256, 0, stream>>>(x, xb, n4);
  }
  {
    int n4 = N1 * KD / 4;
    cvt_f32_bf16_kernel<<<(n4 + 255) / 256, 256, 0, stream>>>(wqkv, wqkvb, n4);
  }
  {
    int n4 = Dsz * KD / 4;
    cvt_f32_bf16_kernel<<<(n4 + 255) / 256, 256, 0, stream>>>(wo, wob, n4);
  }
  rope_tab_kernel<<<(Ssz * 32 + 255) / 256, 256, 0, stream>>>(pos, tab);

  gemm_tn_kernel<0><<<dim3(N1 / 128, Mrows / 128), 256, 0, stream>>>(
      xb, wqkvb, KD, 0, qbuf, kbuf, vtb, tab, nullptr);

  attn_kernel<<<dim3(Ssz / 64 * 64), 256, 0, stream>>>(qbuf, kbuf, vtb, aout);

  gemm_tn_kernel<1><<<dim3(Dsz / 128, Mrows / 128), 256, 0, stream>>>(
      aout, wob, KD, Dsz, nullptr, nullptr, nullptr, nullptr, out);
}

// Round 3
// 295.681 us; speedup vs baseline: 2.2313x; 1.3878x over previous
//
#include <hip/hip_runtime.h>
#include <hip/hip_bf16.h>
#include <math.h>

typedef __bf16 bf16_t;
typedef __attribute__((ext_vector_type(8))) __bf16 bf16x8;
typedef __attribute__((ext_vector_type(4))) __bf16 bf16x4;
typedef __attribute__((ext_vector_type(4))) float f32x4;

#define MFMA_16x16x32(A_, B_, C_) __builtin_amdgcn_mfma_f32_16x16x32_bf16((A_), (B_), (C_), 0, 0, 0)

#define Bsz 4
#define Ssz 2048
#define Dsz 1024
#define Hh 16
#define DKd 64
#define Mrows (Bsz * Ssz)  /* 8192 */
#define N1 (3 * Dsz)       /* 3072 */
#define KD Dsz             /* 1024 */

// ---------------- f32 -> bf16 conversion (x4 vectorized) ----------------
__global__ void cvt_f32_bf16_kernel(const float* __restrict__ src, bf16_t* __restrict__ dst, int n4) {
  int i = blockIdx.x * blockDim.x + threadIdx.x;
  if (i >= n4) return;
  float4 v = reinterpret_cast<const float4*>(src)[i];
  bf16x4 o = {(bf16_t)v.x, (bf16_t)v.y, (bf16_t)v.z, (bf16_t)v.w};
  reinterpret_cast<bf16x4*>(dst)[i] = o;
}

// ---------------- RoPE cos/sin table: [S][32] float2 ----------------
__global__ void rope_tab_kernel(const int* __restrict__ pos, float2* __restrict__ tab) {
  int i = blockIdx.x * blockDim.x + threadIdx.x;
  if (i >= Ssz * 32) return;
  int s = i >> 5, f = i & 31;
  float inv_freq = powf(10000.0f, -(float)(2 * f) / 64.0f);
  float a = (float)pos[s] * inv_freq;
  tab[i] = make_float2(cosf(a), sinf(a));
}

// ---------------- TN GEMM: C[M][N] = A[M][K] * Bt[N][K]^T ----------------
template <int EPI>
__global__ __launch_bounds__(256, 2) void gemm_tn_kernel(
    const bf16_t* __restrict__ A, const bf16_t* __restrict__ Bt, int Kdim, int ldcN,
    bf16_t* __restrict__ qb, bf16_t* __restrict__ kb, bf16_t* __restrict__ vtb,
    const float2* __restrict__ tab, float* __restrict__ fout) {
  constexpr int LDA = 40;
  __shared__ __align__(16) bf16_t As[128 * LDA];
  __shared__ __align__(16) bf16_t Bs[128 * LDA];
  const int t = threadIdx.x;
  const int w = t >> 6, l = t & 63;
  const int lr = l & 15, lk = l >> 4;
  const int wm = w >> 1, wn = w & 1;
  const int m0 = blockIdx.y * 128, n0 = blockIdx.x * 128;

  const int srow = t >> 2;
  const int scol = (t & 3) * 8;
  const bf16_t* gA0 = A + (size_t)(m0 + srow) * Kdim + scol;
  const bf16_t* gA1 = A + (size_t)(m0 + 64 + srow) * Kdim + scol;
  const bf16_t* gB0 = Bt + (size_t)(n0 + srow) * Kdim + scol;
  const bf16_t* gB1 = Bt + (size_t)(n0 + 64 + srow) * Kdim + scol;
  bf16_t* sA0 = As + srow * LDA + scol;
  bf16_t* sA1 = As + (64 + srow) * LDA + scol;
  bf16_t* sB0 = Bs + srow * LDA + scol;
  bf16_t* sB1 = Bs + (64 + srow) * LDA + scol;

  f32x4 acc[4][4] = {};

  for (int kt = 0; kt < Kdim; kt += 32) {
    bf16x8 ra0 = *reinterpret_cast<const bf16x8*>(gA0 + kt);
    bf16x8 ra1 = *reinterpret_cast<const bf16x8*>(gA1 + kt);
    bf16x8 rb0 = *reinterpret_cast<const bf16x8*>(gB0 + kt);
    bf16x8 rb1 = *reinterpret_cast<const bf16x8*>(gB1 + kt);
    __syncthreads();
    *reinterpret_cast<bf16x8*>(sA0) = ra0;
    *reinterpret_cast<bf16x8*>(sA1) = ra1;
    *reinterpret_cast<bf16x8*>(sB0) = rb0;
    *reinterpret_cast<bf16x8*>(sB1) = rb1;
    __syncthreads();
    bf16x8 af[4], bfv[4];
#pragma unroll
    for (int m = 0; m < 4; ++m)
      af[m] = *reinterpret_cast<const bf16x8*>(As + (wm * 64 + m * 16 + lr) * LDA + lk * 8);
#pragma unroll
    for (int n = 0; n < 4; ++n)
      bfv[n] = *reinterpret_cast<const bf16x8*>(Bs + (wn * 64 + n * 16 + lr) * LDA + lk * 8);
#pragma unroll
    for (int m = 0; m < 4; ++m)
#pragma unroll
      for (int n = 0; n < 4; ++n)
        acc[m][n] = MFMA_16x16x32(af[m], bfv[n], acc[m][n]);
  }

  if (EPI == 0) {
#pragma unroll
    for (int n = 0; n < 4; ++n) {
      const int col = n0 + wn * 64 + n * 16 + lr;
      const int sect = col >> 10;
      const int h = (col >> 6) & 15;
      const int dk = col & 63;
#pragma unroll
      for (int m = 0; m < 4; ++m) {
        const int growb = m0 + wm * 64 + m * 16 + lk * 4;
#pragma unroll
        for (int r = 0; r < 4; ++r) {
          const int grow = growb + r;
          const int bb = grow >> 11;
          const int s = grow & (Ssz - 1);
          float v = acc[m][n][r];
          if (sect < 2) {
            const float pv = __shfl_xor(v, 1);
            const float2 cs = tab[(s << 5) | (dk >> 1)];
            float vr = (dk & 1) ? (pv * cs.y + v * cs.x) : (v * cs.x - pv * cs.y);
            const size_t idx = ((size_t)((bb * Hh + h) * Ssz + s)) * DKd + dk;
            if (sect == 0)
              qb[idx] = (bf16_t)(vr * 0.125f);
            else
              kb[idx] = (bf16_t)vr;
          } else {
            vtb[((size_t)(bb * Hh + h) * DKd + dk) * Ssz + s] = (bf16_t)v;
          }
        }
      }
    }
  } else {
#pragma unroll
    for (int m = 0; m < 4; ++m)
#pragma unroll
      for (int r = 0; r < 4; ++r) {
        const int grow = m0 + wm * 64 + m * 16 + lk * 4 + r;
        float* op = fout + (size_t)grow * ldcN + n0 + wn * 64 + lr;
#pragma unroll
        for (int n = 0; n < 4; ++n) op[n * 16] = acc[m][n][r];
      }
  }
}

// ---------------- causal flash attention, LDS-staged K/V ----------------
// 1024 blocks: x=bid&7 (XCD cluster), bh = x*8 + (bid>>3)&7, qt = 15 - bid>>6
// (heavy-first). Block owns 128 q rows; wave w owns rows [32w, 32w+32) of the
// tile as two 16-row subtiles. K/V 64x64 tiles staged in XOR-swizzled LDS
// once per block (4x traffic cut vs per-wave loads), prefetched into regs.
__global__ __launch_bounds__(256, 4) void attn_kernel(
    const bf16_t* __restrict__ qb, const bf16_t* __restrict__ kb,
    const bf16_t* __restrict__ vtb, bf16_t* __restrict__ aout) {
  __shared__ __align__(16) bf16_t Ks[64 * 64];  // [kv][d], 16B-chunk XOR swizzle
  __shared__ __align__(16) bf16_t Vs[64 * 64];  // [d][kv], same swizzle
  __shared__ __align__(16) bf16_t Pl[4][16 * 72];
  const int t = threadIdx.x, w = t >> 6, l = t & 63;
  const int lr = l & 15, lk = l >> 4;
  const int bid = blockIdx.x;
  const int bh = (bid & 7) * 8 + ((bid >> 3) & 7);
  const int qt = 15 - (bid >> 6);
  const int q0 = qt * 128;
  const int sub0 = q0 + w * 32;

  // Q fragments for both 16-row subtiles (scale folded in at QKV epilogue)
  const bf16_t* qbase = qb + ((size_t)bh * Ssz + sub0) * DKd;
  bf16x8 qf[2][2];
#pragma unroll
  for (int s = 0; s < 2; ++s) {
    qf[s][0] = *reinterpret_cast<const bf16x8*>(qbase + (s * 16 + lr) * DKd + lk * 8);
    qf[s][1] = *reinterpret_cast<const bf16x8*>(qbase + (s * 16 + lr) * DKd + 32 + lk * 8);
  }

  f32x4 o[2][4] = {};
  float mrow[2][4], lsum[2][4];
#pragma unroll
  for (int s = 0; s < 2; ++s)
#pragma unroll
    for (int r = 0; r < 4; ++r) { mrow[s][r] = -INFINITY; lsum[s][r] = 0.f; }

  // staging geometry: thread stages 32B (2 chunks) of K and of V
  const int srow = t >> 2;          // 0..63
  const int scc = (t & 3) * 2;      // even chunk 0..6
  const bf16_t* kg = kb + ((size_t)bh * Ssz + srow) * DKd + scc * 8;
  const bf16_t* vg = vtb + ((size_t)bh * DKd + srow) * Ssz + scc * 8;
  bf16_t* ksw0 = Ks + srow * 64 + ((scc ^ (srow & 7)) * 8);
  bf16_t* ksw1 = Ks + srow * 64 + (((scc + 1) ^ (srow & 7)) * 8);
  bf16_t* vsw0 = Vs + srow * 64 + ((scc ^ (srow & 7)) * 8);
  bf16_t* vsw1 = Vs + srow * 64 + (((scc + 1) ^ (srow & 7)) * 8);

  const int kvend = q0 + 128;
  bf16_t* pw = Pl[w];

  bf16x8 pk0 = *reinterpret_cast<const bf16x8*>(kg);
  bf16x8 pk1 = *reinterpret_cast<const bf16x8*>(kg + 8);
  bf16x8 pv0 = *reinterpret_cast<const bf16x8*>(vg);
  bf16x8 pv1 = *reinterpret_cast<const bf16x8*>(vg + 8);

  for (int kv = 0; kv < kvend; kv += 64) {
    __syncthreads();  // previous tile fully consumed
    *reinterpret_cast<bf16x8*>(ksw0) = pk0;
    *reinterpret_cast<bf16x8*>(ksw1) = pk1;
    *reinterpret_cast<bf16x8*>(vsw0) = pv0;
    *reinterpret_cast<bf16x8*>(vsw1) = pv1;
    __syncthreads();
    if (kv + 64 < kvend) {  // prefetch next tile (hidden under compute)
      pk0 = *reinterpret_cast<const bf16x8*>(kg + (size_t)(kv + 64) * DKd);
      pk1 = *reinterpret_cast<const bf16x8*>(kg + (size_t)(kv + 64) * DKd + 8);
      pv0 = *reinterpret_cast<const bf16x8*>(vg + kv + 64);
      pv1 = *reinterpret_cast<const bf16x8*>(vg + kv + 64 + 8);
    }
#pragma unroll
    for (int s = 0; s < 2; ++s) {
      const int subrow = sub0 + s * 16;
      if (kv > subrow + 15) continue;  // fully masked for this subtile (uniform)
      // ---- QK^T: 16q x 64kv ----
      f32x4 sa[4];
#pragma unroll
      for (int n = 0; n < 4; ++n) {
        const int R = n * 16 + lr;
        const bf16x8 b0 = *reinterpret_cast<const bf16x8*>(Ks + R * 64 + ((lk ^ (R & 7)) * 8));
        const bf16x8 b1 = *reinterpret_cast<const bf16x8*>(Ks + R * 64 + (((lk + 4) ^ (R & 7)) * 8));
        f32x4 z = {};
        z = MFMA_16x16x32(qf[s][0], b0, z);
        z = MFMA_16x16x32(qf[s][1], b1, z);
        sa[n] = z;
      }
      // ---- causal mask (diagonal region only) ----
      if (kv + 63 > subrow) {
#pragma unroll
        for (int n = 0; n < 4; ++n) {
          const int col = kv + n * 16 + lr;
#pragma unroll
          for (int r = 0; r < 4; ++r)
            if (col > subrow + lk * 4 + r) sa[n][r] = -INFINITY;
        }
      }
      // ---- online softmax ----
#pragma unroll
      for (int r = 0; r < 4; ++r) {
        float mx = fmaxf(fmaxf(sa[0][r], sa[1][r]), fmaxf(sa[2][r], sa[3][r]));
        mx = fmaxf(mx, __shfl_xor(mx, 1));
        mx = fmaxf(mx, __shfl_xor(mx, 2));
        mx = fmaxf(mx, __shfl_xor(mx, 4));
        mx = fmaxf(mx, __shfl_xor(mx, 8));
        const float mnew = fmaxf(mrow[s][r], mx);
        const float scl = __expf(mrow[s][r] - mnew);
        mrow[s][r] = mnew;
        float ps = 0.f;
#pragma unroll
        for (int n = 0; n < 4; ++n) {
          const float p = __expf(sa[n][r] - mnew);
          sa[n][r] = p;
          ps += p;
        }
        lsum[s][r] = lsum[s][r] * scl + ps;
#pragma unroll
        for (int n = 0; n < 4; ++n) o[s][n][r] *= scl;
      }
      // ---- P -> per-wave LDS (C-frag -> A-frag relayout) ----
#pragma unroll
      for (int r = 0; r < 4; ++r)
#pragma unroll
        for (int n = 0; n < 4; ++n)
          pw[(lk * 4 + r) * 72 + n * 16 + lr] = (bf16_t)sa[n][r];
      const bf16x8 pf0 = *reinterpret_cast<const bf16x8*>(pw + lr * 72 + lk * 8);
      const bf16x8 pf1 = *reinterpret_cast<const bf16x8*>(pw + lr * 72 + 32 + lk * 8);
      // ---- PV from swizzled Vs ----
#pragma unroll
      for (int n = 0; n < 4; ++n) {
        const int R = n * 16 + lr;
        const bf16x8 v0 = *reinterpret_cast<const bf16x8*>(Vs + R * 64 + ((lk ^ (R & 7)) * 8));
        const bf16x8 v1 = *reinterpret_cast<const bf16x8*>(Vs + R * 64 + (((lk + 4) ^ (R & 7)) * 8));
        o[s][n] = MFMA_16x16x32(pf0, v0, o[s][n]);
        o[s][n] = MFMA_16x16x32(pf1, v1, o[s][n]);
      }
    }
  }
  // ---- final denominator reduce + store ----
  const int b_ = bh >> 4, h_ = bh & 15;
#pragma unroll
  for (int s = 0; s < 2; ++s) {
#pragma unroll
    for (int r = 0; r < 4; ++r) {
      float sm = lsum[s][r];
      sm += __shfl_xor(sm, 1);
      sm += __shfl_xor(sm, 2);
      sm += __shfl_xor(sm, 4);
      sm += __shfl_xor(sm, 8);
      const float inv = 1.0f / sm;
      const int srowi = sub0 + s * 16 + lk * 4 + r;
      bf16_t* op = aout + ((size_t)b_ * Ssz + srowi) * Dsz + h_ * DKd;
#pragma unroll
      for (int n = 0; n < 4; ++n) op[n * 16 + lr] = (bf16_t)(o[s][n][r] * inv);
    }
  }
}

extern "C" void kernel_launch(void* const* d_in, const int* in_sizes, int n_in,
                              void* d_out, int out_size, void* d_ws, size_t ws_size,
                              hipStream_t stream) {
  const float* x = (const float*)d_in[0];
  const int* pos = (const int*)d_in[1];
  const float* wqkv = (const float*)d_in[2];
  const float* wo = (const float*)d_in[3];
  float* out = (float*)d_out;

  bf16_t* xb = (bf16_t*)d_ws;
  bf16_t* wqkvb = xb + (size_t)Mrows * KD;
  bf16_t* wob = wqkvb + (size_t)N1 * KD;
  bf16_t* qbuf = wob + (size_t)Dsz * KD;
  bf16_t* kbuf = qbuf + (size_t)64 * Ssz * DKd;
  bf16_t* vtb = kbuf + (size_t)64 * Ssz * DKd;
  float2* tab = (float2*)(vtb + (size_t)64 * Ssz * DKd);
  bf16_t* aout = xb;

  {
    int n4 = Mrows * KD / 4;
    cvt_f32_bf16_kernel<<<(n4 + 255) / 256, 256, 0, stream>>>(x, xb, n4);
  }
  {
    int n4 = N1 * KD / 4;
    cvt_f32_bf16_kernel<<<(n4 + 255) / 256, 256, 0, stream>>>(wqkv, wqkvb, n4);
  }
  {
    int n4 = Dsz * KD / 4;
    cvt_f32_bf16_kernel<<<(n4 + 255) / 256, 256, 0, stream>>>(wo, wob, n4);
  }
  rope_tab_kernel<<<(Ssz * 32 + 255) / 256, 256, 0, stream>>>(pos, tab);

  gemm_tn_kernel<0><<<dim3(N1 / 128, Mrows / 128), 256, 0, stream>>>(
      xb, wqkvb, KD, 0, qbuf, kbuf, vtb, tab, nullptr);

  attn_kernel<<<dim3(16 * 64), 256, 0, stream>>>(qbuf, kbuf, vtb, aout);

  gemm_tn_kernel<1><<<dim3(Dsz / 128, Mrows / 128), 256, 0, stream>>>(
      aout, wob, KD, Dsz, nullptr, nullptr, nullptr, nullptr, out);
}

// Round 4
// 220.228 us; speedup vs baseline: 2.9958x; 1.3426x over previous
//
#include <hip/hip_runtime.h>
#include <hip/hip_bf16.h>
#include <math.h>

typedef __bf16 bf16_t;
typedef __attribute__((ext_vector_type(8))) __bf16 bf16x8;
typedef __attribute__((ext_vector_type(4))) __bf16 bf16x4;
typedef __attribute__((ext_vector_type(4))) float f32x4;

#define MFMA_16x16x32(A_, B_, C_) __builtin_amdgcn_mfma_f32_16x16x32_bf16((A_), (B_), (C_), 0, 0, 0)

#define Bsz 4
#define Ssz 2048
#define Dsz 1024
#define Hh 16
#define DKd 64
#define Mrows (Bsz * Ssz)  /* 8192 */
#define N1 (3 * Dsz)       /* 3072 */
#define KD Dsz             /* 1024 */

// ---------------- f32 -> bf16 conversion (x4 vectorized) ----------------
__global__ void cvt_f32_bf16_kernel(const float* __restrict__ src, bf16_t* __restrict__ dst, int n4) {
  int i = blockIdx.x * blockDim.x + threadIdx.x;
  if (i >= n4) return;
  float4 v = reinterpret_cast<const float4*>(src)[i];
  bf16x4 o = {(bf16_t)v.x, (bf16_t)v.y, (bf16_t)v.z, (bf16_t)v.w};
  reinterpret_cast<bf16x4*>(dst)[i] = o;
}

// ---------------- RoPE cos/sin table: [S][32] float2 ----------------
__global__ void rope_tab_kernel(const int* __restrict__ pos, float2* __restrict__ tab) {
  int i = blockIdx.x * blockDim.x + threadIdx.x;
  if (i >= Ssz * 32) return;
  int s = i >> 5, f = i & 31;
  float inv_freq = powf(10000.0f, -(float)(2 * f) / 64.0f);
  float a = (float)pos[s] * inv_freq;
  tab[i] = make_float2(cosf(a), sinf(a));
}

// ---------------- TN GEMM: C[M][N] = A[M][K] * Bt[N][K]^T ----------------
template <int EPI>
__global__ __launch_bounds__(256, 2) void gemm_tn_kernel(
    const bf16_t* __restrict__ A, const bf16_t* __restrict__ Bt, int Kdim, int ldcN,
    bf16_t* __restrict__ qb, bf16_t* __restrict__ kb, bf16_t* __restrict__ vtb,
    const float2* __restrict__ tab, float* __restrict__ fout) {
  constexpr int LDA = 40;
  __shared__ __align__(16) bf16_t As[128 * LDA];
  __shared__ __align__(16) bf16_t Bs[128 * LDA];
  const int t = threadIdx.x;
  const int w = t >> 6, l = t & 63;
  const int lr = l & 15, lk = l >> 4;
  const int wm = w >> 1, wn = w & 1;
  const int m0 = blockIdx.y * 128, n0 = blockIdx.x * 128;

  const int srow = t >> 2;
  const int scol = (t & 3) * 8;
  const bf16_t* gA0 = A + (size_t)(m0 + srow) * Kdim + scol;
  const bf16_t* gA1 = A + (size_t)(m0 + 64 + srow) * Kdim + scol;
  const bf16_t* gB0 = Bt + (size_t)(n0 + srow) * Kdim + scol;
  const bf16_t* gB1 = Bt + (size_t)(n0 + 64 + srow) * Kdim + scol;
  bf16_t* sA0 = As + srow * LDA + scol;
  bf16_t* sA1 = As + (64 + srow) * LDA + scol;
  bf16_t* sB0 = Bs + srow * LDA + scol;
  bf16_t* sB1 = Bs + (64 + srow) * LDA + scol;

  f32x4 acc[4][4] = {};

  for (int kt = 0; kt < Kdim; kt += 32) {
    bf16x8 ra0 = *reinterpret_cast<const bf16x8*>(gA0 + kt);
    bf16x8 ra1 = *reinterpret_cast<const bf16x8*>(gA1 + kt);
    bf16x8 rb0 = *reinterpret_cast<const bf16x8*>(gB0 + kt);
    bf16x8 rb1 = *reinterpret_cast<const bf16x8*>(gB1 + kt);
    __syncthreads();
    *reinterpret_cast<bf16x8*>(sA0) = ra0;
    *reinterpret_cast<bf16x8*>(sA1) = ra1;
    *reinterpret_cast<bf16x8*>(sB0) = rb0;
    *reinterpret_cast<bf16x8*>(sB1) = rb1;
    __syncthreads();
    bf16x8 af[4], bfv[4];
#pragma unroll
    for (int m = 0; m < 4; ++m)
      af[m] = *reinterpret_cast<const bf16x8*>(As + (wm * 64 + m * 16 + lr) * LDA + lk * 8);
#pragma unroll
    for (int n = 0; n < 4; ++n)
      bfv[n] = *reinterpret_cast<const bf16x8*>(Bs + (wn * 64 + n * 16 + lr) * LDA + lk * 8);
#pragma unroll
    for (int m = 0; m < 4; ++m)
#pragma unroll
      for (int n = 0; n < 4; ++n)
        acc[m][n] = MFMA_16x16x32(af[m], bfv[n], acc[m][n]);
  }

  if (EPI == 0) {
#pragma unroll
    for (int n = 0; n < 4; ++n) {
      const int col = n0 + wn * 64 + n * 16 + lr;
      const int sect = col >> 10;
      const int h = (col >> 6) & 15;
      const int dk = col & 63;
#pragma unroll
      for (int m = 0; m < 4; ++m) {
        const int growb = m0 + wm * 64 + m * 16 + lk * 4;
#pragma unroll
        for (int r = 0; r < 4; ++r) {
          const int grow = growb + r;
          const int bb = grow >> 11;
          const int s = grow & (Ssz - 1);
          float v = acc[m][n][r];
          if (sect < 2) {
            const float pv = __shfl_xor(v, 1);
            const float2 cs = tab[(s << 5) | (dk >> 1)];
            float vr = (dk & 1) ? (pv * cs.y + v * cs.x) : (v * cs.x - pv * cs.y);
            const size_t idx = ((size_t)((bb * Hh + h) * Ssz + s)) * DKd + dk;
            if (sect == 0)
              qb[idx] = (bf16_t)(vr * 0.125f);
            else
              kb[idx] = (bf16_t)vr;
          } else {
            vtb[((size_t)(bb * Hh + h) * DKd + dk) * Ssz + s] = (bf16_t)v;
          }
        }
      }
    }
  } else {
#pragma unroll
    for (int m = 0; m < 4; ++m)
#pragma unroll
      for (int r = 0; r < 4; ++r) {
        const int grow = m0 + wm * 64 + m * 16 + lk * 4 + r;
        float* op = fout + (size_t)grow * ldcN + n0 + wn * 64 + lr;
#pragma unroll
        for (int n = 0; n < 4; ++n) op[n * 16] = acc[m][n][r];
      }
  }
}

// ---------------- causal flash attention, swapped-QK^T / in-lane softmax ----
// S^T = mfma(K_frag, Q_frag): lane holds 16 P values all for q = lane&15
// (k = kv + 16n + 4lk + r). Row reduce = in-lane tree + 2 shfl_xor (lk groups).
// PV: P is the B-operand in natural in-lane order; V's kv axis is PERMUTED at
// LDS staging (pos 32m+8lk+4h+r <- kv 32m+16h+4lk+r) so the A-operand k-slots
// line up with P's layout. No P relayout, no cross-lane exchange.
__global__ __launch_bounds__(256, 3) void attn_kernel(
    const bf16_t* __restrict__ qb, const bf16_t* __restrict__ kb,
    const bf16_t* __restrict__ vtb, bf16_t* __restrict__ aout) {
  __shared__ __align__(16) bf16_t Ks[64 * 64];  // [kv][d], 16B-chunk XOR swizzle
  __shared__ __align__(16) bf16_t Vs[64 * 64];  // [d][kv-permuted], same swizzle
  const int t = threadIdx.x, w = t >> 6, l = t & 63;
  const int lr = l & 15, lk = l >> 4;
  const int bid = blockIdx.x;
  const int bh = (bid & 7) * 8 + ((bid >> 3) & 7);
  const int qt = 15 - (bid >> 6);  // heavy-first
  const int q0 = qt * 128;
  const int sub0 = q0 + w * 32;

  // Q as B-frag: lane lr = q row, chunk lk*8 over d
  const bf16_t* qbase = qb + ((size_t)bh * Ssz + sub0) * DKd;
  bf16x8 qf[2][2];
#pragma unroll
  for (int s = 0; s < 2; ++s) {
    qf[s][0] = *reinterpret_cast<const bf16x8*>(qbase + (s * 16 + lr) * DKd + lk * 8);
    qf[s][1] = *reinterpret_cast<const bf16x8*>(qbase + (s * 16 + lr) * DKd + 32 + lk * 8);
  }

  f32x4 o[2][4] = {};                 // o^T: rows d=16n+4lk+r, col q=lr
  float mrow[2] = {-INFINITY, -INFINITY};
  float lsum[2] = {0.f, 0.f};

  // staging: thread stages 2 chunks (32B) of K and of V
  const int srow = t >> 2;       // K: kv row / V: d row
  const int scc = (t & 3) * 2;   // chunk 0..7 (even), +1
  const bf16_t* kg = kb + ((size_t)bh * Ssz + srow) * DKd + scc * 8;
  const bf16_t* vg = vtb + ((size_t)bh * DKd + srow) * Ssz + scc * 8;
  bf16_t* ksw0 = Ks + srow * 64 + ((scc ^ (srow & 7)) * 8);
  bf16_t* ksw1 = Ks + srow * 64 + (((scc + 1) ^ (srow & 7)) * 8);
  // V permuted write pointers (loop-invariant): chunk c holds kv 8c..8c+7;
  // kv 8c+i goes to pos B + (i<4 ? i : 8+(i&3)), B = 32(c>>2)+16(c&1)+4((c&3)>>1)
  bf16_t* vw[4];
#pragma unroll
  for (int u = 0; u < 2; ++u) {
    const int c = scc + u;
    const int B = 32 * (c >> 2) + 16 * (c & 1) + 4 * ((c & 3) >> 1);
    const int ch = B >> 3, off = B & 7;
    vw[2 * u] = Vs + srow * 64 + ((ch ^ (srow & 7)) * 8) + off;
    vw[2 * u + 1] = Vs + srow * 64 + (((ch + 1) ^ (srow & 7)) * 8) + off;
  }

  const int kvend = q0 + 128;
  bf16x8 pk0 = *reinterpret_cast<const bf16x8*>(kg);
  bf16x8 pk1 = *reinterpret_cast<const bf16x8*>(kg + 8);
  bf16x8 pv0 = *reinterpret_cast<const bf16x8*>(vg);
  bf16x8 pv1 = *reinterpret_cast<const bf16x8*>(vg + 8);

  for (int kv = 0; kv < kvend; kv += 64) {
    __syncthreads();
    *reinterpret_cast<bf16x8*>(ksw0) = pk0;
    *reinterpret_cast<bf16x8*>(ksw1) = pk1;
    *reinterpret_cast<bf16x4*>(vw[0]) = __builtin_shufflevector(pv0, pv0, 0, 1, 2, 3);
    *reinterpret_cast<bf16x4*>(vw[1]) = __builtin_shufflevector(pv0, pv0, 4, 5, 6, 7);
    *reinterpret_cast<bf16x4*>(vw[2]) = __builtin_shufflevector(pv1, pv1, 0, 1, 2, 3);
    *reinterpret_cast<bf16x4*>(vw[3]) = __builtin_shufflevector(pv1, pv1, 4, 5, 6, 7);
    __syncthreads();
    if (kv + 64 < kvend) {
      pk0 = *reinterpret_cast<const bf16x8*>(kg + (size_t)(kv + 64) * DKd);
      pk1 = *reinterpret_cast<const bf16x8*>(kg + (size_t)(kv + 64) * DKd + 8);
      pv0 = *reinterpret_cast<const bf16x8*>(vg + kv + 64);
      pv1 = *reinterpret_cast<const bf16x8*>(vg + kv + 64 + 8);
    }
#pragma unroll
    for (int s = 0; s < 2; ++s) {
      const int subrow = sub0 + s * 16;
      if (kv > subrow + 15) continue;  // fully masked (wave-uniform)
      // ---- S^T = K·Q^T : sa[n][r] = S[k = kv+16n+4lk+r][q = lr] ----
      f32x4 sa[4];
#pragma unroll
      for (int n = 0; n < 4; ++n) {
        const int R = n * 16 + lr;
        const bf16x8 a0 = *reinterpret_cast<const bf16x8*>(Ks + R * 64 + ((lk ^ (R & 7)) * 8));
        const bf16x8 a1 = *reinterpret_cast<const bf16x8*>(Ks + R * 64 + (((lk + 4) ^ (R & 7)) * 8));
        f32x4 z = {};
        z = MFMA_16x16x32(a0, qf[s][0], z);
        z = MFMA_16x16x32(a1, qf[s][1], z);
        sa[n] = z;
      }
      // ---- causal mask (diagonal region only) ----
      if (kv + 63 > subrow) {
        const int qrow = subrow + lr;
        const int kbase = kv + lk * 4;
#pragma unroll
        for (int n = 0; n < 4; ++n)
#pragma unroll
          for (int r = 0; r < 4; ++r)
            if (kbase + n * 16 + r > qrow) sa[n][r] = -INFINITY;
      }
      // ---- in-lane online softmax (lane owns q=lr, 16 k's) ----
      float mx = fmaxf(fmaxf(fmaxf(sa[0][0], sa[0][1]), fmaxf(sa[0][2], sa[0][3])),
                       fmaxf(fmaxf(sa[1][0], sa[1][1]), fmaxf(sa[1][2], sa[1][3])));
      mx = fmaxf(mx, fmaxf(fmaxf(fmaxf(sa[2][0], sa[2][1]), fmaxf(sa[2][2], sa[2][3])),
                           fmaxf(fmaxf(sa[3][0], sa[3][1]), fmaxf(sa[3][2], sa[3][3]))));
      mx = fmaxf(mx, __shfl_xor(mx, 16));
      mx = fmaxf(mx, __shfl_xor(mx, 32));
      const float mnew = fmaxf(mrow[s], mx);
      const float scl = __expf(mrow[s] - mnew);
      mrow[s] = mnew;
      float ps = 0.f;
#pragma unroll
      for (int n = 0; n < 4; ++n)
#pragma unroll
        for (int r = 0; r < 4; ++r) {
          const float p = __expf(sa[n][r] - mnew);
          sa[n][r] = p;
          ps += p;
        }
      lsum[s] = lsum[s] * scl + ps;
#pragma unroll
      for (int n = 0; n < 4; ++n)
#pragma unroll
        for (int r = 0; r < 4; ++r) o[s][n][r] *= scl;
      // ---- pack P into B-frags (pure in-lane; k-order matches Vs permute) ----
      bf16x8 pb0, pb1;
#pragma unroll
      for (int r = 0; r < 4; ++r) {
        pb0[r] = (bf16_t)sa[0][r];
        pb0[4 + r] = (bf16_t)sa[1][r];
        pb1[r] = (bf16_t)sa[2][r];
        pb1[4 + r] = (bf16_t)sa[3][r];
      }
      // ---- o^T += V^T · P : A = Vs (permuted kv), B = pb ----
#pragma unroll
      for (int n = 0; n < 4; ++n) {
        const int R = n * 16 + lr;
        const bf16x8 v0 = *reinterpret_cast<const bf16x8*>(Vs + R * 64 + ((lk ^ (R & 7)) * 8));
        const bf16x8 v1 = *reinterpret_cast<const bf16x8*>(Vs + R * 64 + (((lk + 4) ^ (R & 7)) * 8));
        o[s][n] = MFMA_16x16x32(v0, pb0, o[s][n]);
        o[s][n] = MFMA_16x16x32(v1, pb1, o[s][n]);
      }
    }
  }
  // ---- final reduce + store (o^T: lane has 16 d-values for q = lr) ----
  const int b_ = bh >> 4, h_ = bh & 15;
#pragma unroll
  for (int s = 0; s < 2; ++s) {
    float sm = lsum[s];
    sm += __shfl_xor(sm, 16);
    sm += __shfl_xor(sm, 32);
    const float inv = 1.0f / sm;
    const int qrow = sub0 + s * 16 + lr;
    bf16_t* op = aout + ((size_t)b_ * Ssz + qrow) * Dsz + h_ * DKd + lk * 4;
#pragma unroll
    for (int n = 0; n < 4; ++n) {
      const bf16x4 ov = {(bf16_t)(o[s][n][0] * inv), (bf16_t)(o[s][n][1] * inv),
                         (bf16_t)(o[s][n][2] * inv), (bf16_t)(o[s][n][3] * inv)};
      *reinterpret_cast<bf16x4*>(op + n * 16) = ov;
    }
  }
}

extern "C" void kernel_launch(void* const* d_in, const int* in_sizes, int n_in,
                              void* d_out, int out_size, void* d_ws, size_t ws_size,
                              hipStream_t stream) {
  const float* x = (const float*)d_in[0];
  const int* pos = (const int*)d_in[1];
  const float* wqkv = (const float*)d_in[2];
  const float* wo = (const float*)d_in[3];
  float* out = (float*)d_out;

  bf16_t* xb = (bf16_t*)d_ws;
  bf16_t* wqkvb = xb + (size_t)Mrows * KD;
  bf16_t* wob = wqkvb + (size_t)N1 * KD;
  bf16_t* qbuf = wob + (size_t)Dsz * KD;
  bf16_t* kbuf = qbuf + (size_t)64 * Ssz * DKd;
  bf16_t* vtb = kbuf + (size_t)64 * Ssz * DKd;
  float2* tab = (float2*)(vtb + (size_t)64 * Ssz * DKd);
  bf16_t* aout = xb;

  {
    int n4 = Mrows * KD / 4;
    cvt_f32_bf16_kernel<<<(n4 + 255) / 256, 256, 0, stream>>>(x, xb, n4);
  }
  {
    int n4 = N1 * KD / 4;
    cvt_f32_bf16_kernel<<<(n4 + 255) / 256, 256, 0, stream>>>(wqkv, wqkvb, n4);
  }
  {
    int n4 = Dsz * KD / 4;
    cvt_f32_bf16_kernel<<<(n4 + 255) / 256, 256, 0, stream>>>(wo, wob, n4);
  }
  rope_tab_kernel<<<(Ssz * 32 + 255) / 256, 256, 0, stream>>>(pos, tab);

  gemm_tn_kernel<0><<<dim3(N1 / 128, Mrows / 128), 256, 0, stream>>>(
      xb, wqkvb, KD, 0, qbuf, kbuf, vtb, tab, nullptr);

  attn_kernel<<<dim3(16 * 64), 256, 0, stream>>>(qbuf, kbuf, vtb, aout);

  gemm_tn_kernel<1><<<dim3(Dsz / 128, Mrows / 128), 256, 0, stream>>>(
      aout, wob, KD, Dsz, nullptr, nullptr, nullptr, nullptr, out);
}

// Round 5
// 213.450 us; speedup vs baseline: 3.0909x; 1.0318x over previous
//
#include <hip/hip_runtime.h>
#include <hip/hip_bf16.h>
#include <math.h>

typedef __bf16 bf16_t;
typedef __attribute__((ext_vector_type(8))) __bf16 bf16x8;
typedef __attribute__((ext_vector_type(4))) __bf16 bf16x4;
typedef __attribute__((ext_vector_type(4))) float f32x4;

#define MFMA_16x16x32(A_, B_, C_) __builtin_amdgcn_mfma_f32_16x16x32_bf16((A_), (B_), (C_), 0, 0, 0)

#define Bsz 4
#define Ssz 2048
#define Dsz 1024
#define Hh 16
#define DKd 64
#define Mrows (Bsz * Ssz)  /* 8192 */
#define N1 (3 * Dsz)       /* 3072 */
#define KD Dsz             /* 1024 */

// ---------------- f32 -> bf16 conversion (x4 vectorized) ----------------
__global__ void cvt_f32_bf16_kernel(const float* __restrict__ src, bf16_t* __restrict__ dst, int n4) {
  int i = blockIdx.x * blockDim.x + threadIdx.x;
  if (i >= n4) return;
  float4 v = reinterpret_cast<const float4*>(src)[i];
  bf16x4 o = {(bf16_t)v.x, (bf16_t)v.y, (bf16_t)v.z, (bf16_t)v.w};
  reinterpret_cast<bf16x4*>(dst)[i] = o;
}

// ---------------- RoPE cos/sin table: [S][32] float2 ----------------
__global__ void rope_tab_kernel(const int* __restrict__ pos, float2* __restrict__ tab) {
  int i = blockIdx.x * blockDim.x + threadIdx.x;
  if (i >= Ssz * 32) return;
  int s = i >> 5, f = i & 31;
  float inv_freq = powf(10000.0f, -(float)(2 * f) / 64.0f);
  float a = (float)pos[s] * inv_freq;
  tab[i] = make_float2(cosf(a), sinf(a));
}

// ---------------- TN GEMM: C[M][N] = A[M][K] * Bt[N][K]^T ----------------
// m97 structure: 128x128 tile, BK=32, 4 waves (2x2), global_load_lds width=16
// (linear LDS dest), source-side chunk XOR-swizzle (chunk ^= (row>>1)&3) with
// matching ds_read swizzle -> 2-way (free) bank access. 2 barriers / K-step.
template <int EPI>
__global__ __launch_bounds__(256, 3) void gemm_tn_kernel(
    const bf16_t* __restrict__ A, const bf16_t* __restrict__ Bt, int Kdim, int ldcN,
    bf16_t* __restrict__ qb, bf16_t* __restrict__ kb, bf16_t* __restrict__ vtb,
    const float2* __restrict__ tab, float* __restrict__ fout) {
  __shared__ __align__(16) bf16_t As[128 * 32];
  __shared__ __align__(16) bf16_t Bs[128 * 32];
  const int t = threadIdx.x;
  const int w = t >> 6, l = t & 63;
  const int lr = l & 15, lk = l >> 4;
  const int wm = w >> 1, wn = w & 1;
  const int m0 = blockIdx.y * 128, n0 = blockIdx.x * 128;

  // staging: round j covers tile rows j*64 + (t>>2); lane's LDS chunk = t&3,
  // whose DATA is global chunk (t&3) ^ ((row>>1)&3) = (t&3) ^ ((t>>3)&3).
  const int srow = t >> 2;
  const int schunk = (t & 3) ^ ((t >> 3) & 3);
  const bf16_t* gA = A + (size_t)(m0 + srow) * Kdim + schunk * 8;
  const bf16_t* gB = Bt + (size_t)(n0 + srow) * Kdim + schunk * 8;
  // wave-uniform LDS bases (lane*16B appended by HW)
  bf16_t* sA0 = As + (size_t)(w * 16) * 32;
  bf16_t* sA1 = As + (size_t)(64 + w * 16) * 32;
  bf16_t* sB0 = Bs + (size_t)(w * 16) * 32;
  bf16_t* sB1 = Bs + (size_t)(64 + w * 16) * 32;

  f32x4 acc[4][4] = {};

  for (int kt = 0; kt < Kdim; kt += 32) {
    __builtin_amdgcn_global_load_lds(gA + kt, sA0, 16, 0, 0);
    __builtin_amdgcn_global_load_lds(gA + (size_t)64 * Kdim + kt, sA1, 16, 0, 0);
    __builtin_amdgcn_global_load_lds(gB + kt, sB0, 16, 0, 0);
    __builtin_amdgcn_global_load_lds(gB + (size_t)64 * Kdim + kt, sB1, 16, 0, 0);
    __syncthreads();  // compiler drains vmcnt(0) before s_barrier
    bf16x8 af[4], bfv[4];
    const int rsw = (lr >> 1) & 3;  // read-side swizzle, matches source permute
#pragma unroll
    for (int m = 0; m < 4; ++m)
      af[m] = *reinterpret_cast<const bf16x8*>(As + (wm * 64 + m * 16 + lr) * 32 + ((lk ^ rsw) * 8));
#pragma unroll
    for (int n = 0; n < 4; ++n)
      bfv[n] = *reinterpret_cast<const bf16x8*>(Bs + (wn * 64 + n * 16 + lr) * 32 + ((lk ^ rsw) * 8));
#pragma unroll
    for (int m = 0; m < 4; ++m)
#pragma unroll
      for (int n = 0; n < 4; ++n)
        acc[m][n] = MFMA_16x16x32(af[m], bfv[n], acc[m][n]);
    __syncthreads();  // tile consumed before next overwrite
  }

  if (EPI == 0) {
#pragma unroll
    for (int n = 0; n < 4; ++n) {
      const int col = n0 + wn * 64 + n * 16 + lr;
      const int sect = col >> 10;
      const int h = (col >> 6) & 15;
      const int dk = col & 63;
#pragma unroll
      for (int m = 0; m < 4; ++m) {
        const int growb = m0 + wm * 64 + m * 16 + lk * 4;
#pragma unroll
        for (int r = 0; r < 4; ++r) {
          const int grow = growb + r;
          const int bb = grow >> 11;
          const int s = grow & (Ssz - 1);
          float v = acc[m][n][r];
          if (sect < 2) {
            const float pv = __shfl_xor(v, 1);
            const float2 cs = tab[(s << 5) | (dk >> 1)];
            float vr = (dk & 1) ? (pv * cs.y + v * cs.x) : (v * cs.x - pv * cs.y);
            const size_t idx = ((size_t)((bb * Hh + h) * Ssz + s)) * DKd + dk;
            if (sect == 0)
              qb[idx] = (bf16_t)(vr * 0.125f);
            else
              kb[idx] = (bf16_t)vr;
          } else {
            vtb[((size_t)(bb * Hh + h) * DKd + dk) * Ssz + s] = (bf16_t)v;
          }
        }
      }
    }
  } else {
#pragma unroll
    for (int m = 0; m < 4; ++m)
#pragma unroll
      for (int r = 0; r < 4; ++r) {
        const int grow = m0 + wm * 64 + m * 16 + lk * 4 + r;
        float* op = fout + (size_t)grow * ldcN + n0 + wn * 64 + lr;
#pragma unroll
        for (int n = 0; n < 4; ++n) op[n * 16] = acc[m][n][r];
      }
  }
}

// ---------------- causal flash attention, swapped-QK^T / in-lane softmax ----
__global__ __launch_bounds__(256, 3) void attn_kernel(
    const bf16_t* __restrict__ qb, const bf16_t* __restrict__ kb,
    const bf16_t* __restrict__ vtb, bf16_t* __restrict__ aout) {
  __shared__ __align__(16) bf16_t Ks[64 * 64];
  __shared__ __align__(16) bf16_t Vs[64 * 64];
  const int t = threadIdx.x, w = t >> 6, l = t & 63;
  const int lr = l & 15, lk = l >> 4;
  const int bid = blockIdx.x;
  const int bh = (bid & 7) * 8 + ((bid >> 3) & 7);
  const int qt = 15 - (bid >> 6);  // heavy-first
  const int q0 = qt * 128;
  const int sub0 = q0 + w * 32;

  const bf16_t* qbase = qb + ((size_t)bh * Ssz + sub0) * DKd;
  bf16x8 qf[2][2];
#pragma unroll
  for (int s = 0; s < 2; ++s) {
    qf[s][0] = *reinterpret_cast<const bf16x8*>(qbase + (s * 16 + lr) * DKd + lk * 8);
    qf[s][1] = *reinterpret_cast<const bf16x8*>(qbase + (s * 16 + lr) * DKd + 32 + lk * 8);
  }

  f32x4 o[2][4] = {};
  float mrow[2] = {-INFINITY, -INFINITY};
  float lsum[2] = {0.f, 0.f};

  const int srow = t >> 2;
  const int scc = (t & 3) * 2;
  const bf16_t* kg = kb + ((size_t)bh * Ssz + srow) * DKd + scc * 8;
  const bf16_t* vg = vtb + ((size_t)bh * DKd + srow) * Ssz + scc * 8;
  bf16_t* ksw0 = Ks + srow * 64 + ((scc ^ (srow & 7)) * 8);
  bf16_t* ksw1 = Ks + srow * 64 + (((scc + 1) ^ (srow & 7)) * 8);
  bf16_t* vw[4];
#pragma unroll
  for (int u = 0; u < 2; ++u) {
    const int c = scc + u;
    const int B = 32 * (c >> 2) + 16 * (c & 1) + 4 * ((c & 3) >> 1);
    const int ch = B >> 3, off = B & 7;
    vw[2 * u] = Vs + srow * 64 + ((ch ^ (srow & 7)) * 8) + off;
    vw[2 * u + 1] = Vs + srow * 64 + (((ch + 1) ^ (srow & 7)) * 8) + off;
  }

  const int kvend = q0 + 128;
  bf16x8 pk0 = *reinterpret_cast<const bf16x8*>(kg);
  bf16x8 pk1 = *reinterpret_cast<const bf16x8*>(kg + 8);
  bf16x8 pv0 = *reinterpret_cast<const bf16x8*>(vg);
  bf16x8 pv1 = *reinterpret_cast<const bf16x8*>(vg + 8);

  for (int kv = 0; kv < kvend; kv += 64) {
    __syncthreads();
    *reinterpret_cast<bf16x8*>(ksw0) = pk0;
    *reinterpret_cast<bf16x8*>(ksw1) = pk1;
    *reinterpret_cast<bf16x4*>(vw[0]) = __builtin_shufflevector(pv0, pv0, 0, 1, 2, 3);
    *reinterpret_cast<bf16x4*>(vw[1]) = __builtin_shufflevector(pv0, pv0, 4, 5, 6, 7);
    *reinterpret_cast<bf16x4*>(vw[2]) = __builtin_shufflevector(pv1, pv1, 0, 1, 2, 3);
    *reinterpret_cast<bf16x4*>(vw[3]) = __builtin_shufflevector(pv1, pv1, 4, 5, 6, 7);
    __syncthreads();
    if (kv + 64 < kvend) {
      pk0 = *reinterpret_cast<const bf16x8*>(kg + (size_t)(kv + 64) * DKd);
      pk1 = *reinterpret_cast<const bf16x8*>(kg + (size_t)(kv + 64) * DKd + 8);
      pv0 = *reinterpret_cast<const bf16x8*>(vg + kv + 64);
      pv1 = *reinterpret_cast<const bf16x8*>(vg + kv + 64 + 8);
    }
#pragma unroll
    for (int s = 0; s < 2; ++s) {
      const int subrow = sub0 + s * 16;
      if (kv > subrow + 15) continue;
      f32x4 sa[4];
#pragma unroll
      for (int n = 0; n < 4; ++n) {
        const int R = n * 16 + lr;
        const bf16x8 a0 = *reinterpret_cast<const bf16x8*>(Ks + R * 64 + ((lk ^ (R & 7)) * 8));
        const bf16x8 a1 = *reinterpret_cast<const bf16x8*>(Ks + R * 64 + (((lk + 4) ^ (R & 7)) * 8));
        f32x4 z = {};
        z = MFMA_16x16x32(a0, qf[s][0], z);
        z = MFMA_16x16x32(a1, qf[s][1], z);
        sa[n] = z;
      }
      if (kv + 63 > subrow) {
        const int qrow = subrow + lr;
        const int kbase = kv + lk * 4;
#pragma unroll
        for (int n = 0; n < 4; ++n)
#pragma unroll
          for (int r = 0; r < 4; ++r)
            if (kbase + n * 16 + r > qrow) sa[n][r] = -INFINITY;
      }
      float mx = fmaxf(fmaxf(fmaxf(sa[0][0], sa[0][1]), fmaxf(sa[0][2], sa[0][3])),
                       fmaxf(fmaxf(sa[1][0], sa[1][1]), fmaxf(sa[1][2], sa[1][3])));
      mx = fmaxf(mx, fmaxf(fmaxf(fmaxf(sa[2][0], sa[2][1]), fmaxf(sa[2][2], sa[2][3])),
                           fmaxf(fmaxf(sa[3][0], sa[3][1]), fmaxf(sa[3][2], sa[3][3]))));
      mx = fmaxf(mx, __shfl_xor(mx, 16));
      mx = fmaxf(mx, __shfl_xor(mx, 32));
      const float mnew = fmaxf(mrow[s], mx);
      const float scl = __expf(mrow[s] - mnew);
      mrow[s] = mnew;
      float ps = 0.f;
#pragma unroll
      for (int n = 0; n < 4; ++n)
#pragma unroll
        for (int r = 0; r < 4; ++r) {
          const float p = __expf(sa[n][r] - mnew);
          sa[n][r] = p;
          ps += p;
        }
      lsum[s] = lsum[s] * scl + ps;
#pragma unroll
      for (int n = 0; n < 4; ++n)
#pragma unroll
        for (int r = 0; r < 4; ++r) o[s][n][r] *= scl;
      bf16x8 pb0, pb1;
#pragma unroll
      for (int r = 0; r < 4; ++r) {
        pb0[r] = (bf16_t)sa[0][r];
        pb0[4 + r] = (bf16_t)sa[1][r];
        pb1[r] = (bf16_t)sa[2][r];
        pb1[4 + r] = (bf16_t)sa[3][r];
      }
#pragma unroll
      for (int n = 0; n < 4; ++n) {
        const int R = n * 16 + lr;
        const bf16x8 v0 = *reinterpret_cast<const bf16x8*>(Vs + R * 64 + ((lk ^ (R & 7)) * 8));
        const bf16x8 v1 = *reinterpret_cast<const bf16x8*>(Vs + R * 64 + (((lk + 4) ^ (R & 7)) * 8));
        o[s][n] = MFMA_16x16x32(v0, pb0, o[s][n]);
        o[s][n] = MFMA_16x16x32(v1, pb1, o[s][n]);
      }
    }
  }
  const int b_ = bh >> 4, h_ = bh & 15;
#pragma unroll
  for (int s = 0; s < 2; ++s) {
    float sm = lsum[s];
    sm += __shfl_xor(sm, 16);
    sm += __shfl_xor(sm, 32);
    const float inv = 1.0f / sm;
    const int qrow = sub0 + s * 16 + lr;
    bf16_t* op = aout + ((size_t)b_ * Ssz + qrow) * Dsz + h_ * DKd + lk * 4;
#pragma unroll
    for (int n = 0; n < 4; ++n) {
      const bf16x4 ov = {(bf16_t)(o[s][n][0] * inv), (bf16_t)(o[s][n][1] * inv),
                         (bf16_t)(o[s][n][2] * inv), (bf16_t)(o[s][n][3] * inv)};
      *reinterpret_cast<bf16x4*>(op + n * 16) = ov;
    }
  }
}

extern "C" void kernel_launch(void* const* d_in, const int* in_sizes, int n_in,
                              void* d_out, int out_size, void* d_ws, size_t ws_size,
                              hipStream_t stream) {
  const float* x = (const float*)d_in[0];
  const int* pos = (const int*)d_in[1];
  const float* wqkv = (const float*)d_in[2];
  const float* wo = (const float*)d_in[3];
  float* out = (float*)d_out;

  bf16_t* xb = (bf16_t*)d_ws;
  bf16_t* wqkvb = xb + (size_t)Mrows * KD;
  bf16_t* wob = wqkvb + (size_t)N1 * KD;
  bf16_t* qbuf = wob + (size_t)Dsz * KD;
  bf16_t* kbuf = qbuf + (size_t)64 * Ssz * DKd;
  bf16_t* vtb = kbuf + (size_t)64 * Ssz * DKd;
  float2* tab = (float2*)(vtb + (size_t)64 * Ssz * DKd);
  bf16_t* aout = xb;

  {
    int n4 = Mrows * KD / 4;
    cvt_f32_bf16_kernel<<<(n4 + 255) / 256, 256, 0, stream>>>(x, xb, n4);
  }
  {
    int n4 = N1 * KD / 4;
    cvt_f32_bf16_kernel<<<(n4 + 255) / 256, 256, 0, stream>>>(wqkv, wqkvb, n4);
  }
  {
    int n4 = Dsz * KD / 4;
    cvt_f32_bf16_kernel<<<(n4 + 255) / 256, 256, 0, stream>>>(wo, wob, n4);
  }
  rope_tab_kernel<<<(Ssz * 32 + 255) / 256, 256, 0, stream>>>(pos, tab);

  gemm_tn_kernel<0><<<dim3(N1 / 128, Mrows / 128), 256, 0, stream>>>(
      xb, wqkvb, KD, 0, qbuf, kbuf, vtb, tab, nullptr);

  attn_kernel<<<dim3(16 * 64), 256, 0, stream>>>(qbuf, kbuf, vtb, aout);

  gemm_tn_kernel<1><<<dim3(Dsz / 128, Mrows / 128), 256, 0, stream>>>(
      aout, wob, KD, Dsz, nullptr, nullptr, nullptr, nullptr, out);
}